// Round 1
// baseline (222.939 us; speedup 1.0000x reference)
//
#include <hip/hip_runtime.h>
#include <math.h>

#define EPSC 1e-6f
#define THETAC 1e-3f
#define C1C 1e-4f
#define C2C 9e-4f
#define DEN_EPS 1e-12f

constexpr int Bn = 4, Cn = 16, Hn = 512, Wn = 512;
constexpr int HW = Hn * Wn;          // 262144
constexpr int NP = Bn * HW;          // 1048576
constexpr int NX = Bn * Cn * HW;     // 16777216
constexpr int TS = 32;

__device__ __forceinline__ int refl(int i, int n) {
    if (i < 0) i = -i;
    if (i >= n) i = 2 * n - 2 - i;
    return i;
}

// ---------------- K1: Xs = mean over channels ----------------
__global__ void k_xs(const float* __restrict__ X, float* __restrict__ Xs) {
    int p = blockIdx.x * 256 + threadIdx.x;
    if (p >= NP) return;
    int b = p / HW, off = p % HW;
    const float* xp = X + (size_t)b * Cn * HW + off;
    float s = 0.f;
#pragma unroll
    for (int c = 0; c < Cn; c++) s += xp[(size_t)c * HW];
    Xs[p] = s * (1.0f / Cn);
}

// ---------------- K2: chi + per-block {sum,min} ----------------
__global__ void k_chi(const float* __restrict__ G, float* __restrict__ chi,
                      float* __restrict__ psum, float* __restrict__ pmin) {
    __shared__ float ssum[256], smin[256];
    int t = threadIdx.x;
    int base = blockIdx.x * 1024;
    float ls = 0.f, lm = 1e30f;
#pragma unroll
    for (int k = 0; k < 4; k++) {
        int p = base + t + k * 256;
        int off = p % HW;
        int y = off / Wn, x = off % Wn;
        float g = G[p];
        float gx = (x < Wn - 1) ? G[p + 1] - g : 0.f;
        float gy = (y < Hn - 1) ? G[p + Wn] - g : 0.f;
        float c = sqrtf(gx * gx + gy * gy + EPSC);
        chi[p] = c;
        ls += c;
        lm = fminf(lm, c);
    }
    ssum[t] = ls; smin[t] = lm;
    __syncthreads();
    for (int s = 128; s > 0; s >>= 1) {
        if (t < s) { ssum[t] += ssum[t + s]; smin[t] = fminf(smin[t], smin[t + s]); }
        __syncthreads();
    }
    if (t == 0) { psum[blockIdx.x] = ssum[0]; pmin[blockIdx.x] = smin[0]; }
}

// K2b: reduce 256 partials per batch -> mu_chi, eta
__global__ void k_chired(const float* __restrict__ psum, const float* __restrict__ pmin,
                         float* __restrict__ sc) {
    __shared__ float ssum[256], smin[256];
    int t = threadIdx.x, b = blockIdx.x;
    ssum[t] = psum[b * 256 + t];
    smin[t] = pmin[b * 256 + t];
    __syncthreads();
    for (int s = 128; s > 0; s >>= 1) {
        if (t < s) { ssum[t] += ssum[t + s]; smin[t] = fminf(smin[t], smin[t + s]); }
        __syncthreads();
    }
    if (t == 0) {
        float mu = ssum[0] / (float)HW;
        sc[b] = mu;                          // mu_chi
        sc[4 + b] = fmaxf(mu - smin[0], EPSC); // eta
    }
}

// ---------------- K4/K5: tiled ssim + var(G) at radius RAD ----------------
template <int RAD, bool WRITE_MUG>
__global__ void k_ssim(const float* __restrict__ Xs, const float* __restrict__ G,
                       float* __restrict__ tau, float* __restrict__ varg,
                       float* __restrict__ muG) {
    constexpr int HALO = TS + 2 * RAD;
    constexpr int K = 2 * RAD + 1;
    __shared__ float sx[HALO * HALO], sg[HALO * HALO], hs[HALO * TS];
    int t = threadIdx.x;
    int b = blockIdx.y;
    constexpr int tiles_x = Wn / TS;
    int tx0 = (blockIdx.x % tiles_x) * TS;
    int ty0 = (blockIdx.x / tiles_x) * TS;
    const float* Gp = G + (size_t)b * HW;
    const float* Xp = Xs + (size_t)b * HW;
    for (int i = t; i < HALO * HALO; i += 256) {
        int ly = i / HALO, lx = i % HALO;
        int gy = refl(ty0 - RAD + ly, Hn), gx = refl(tx0 - RAD + lx, Wn);
        sx[i] = Xp[gy * Wn + gx];
        sg[i] = Gp[gy * Wn + gx];
    }
    __syncthreads();
    int otx = t % TS, oty0 = t / TS;   // 8 row-groups, 4 rows each
    float acc[5][4];
    const float inv_area = 1.0f / (float)(K * K);
#pragma unroll
    for (int p = 0; p < 5; p++) {
        for (int i = t; i < HALO * TS; i += 256) {
            int y = i / TS, ox = i % TS;
            float s = 0.f;
#pragma unroll
            for (int dx = 0; dx < K; dx++) {
                int idx = y * HALO + ox + dx;
                float xv = sx[idx], gv = sg[idx];
                float v = (p == 0) ? xv : (p == 1) ? gv : (p == 2) ? xv * xv
                          : (p == 3) ? gv * gv : xv * gv;
                s += v;
            }
            hs[i] = s;
        }
        __syncthreads();
#pragma unroll
        for (int k = 0; k < 4; k++) {
            int row = oty0 + k * 8;
            float s = 0.f;
#pragma unroll
            for (int dy = 0; dy < K; dy++) s += hs[(row + dy) * TS + otx];
            acc[p][k] = s * inv_area;
        }
        __syncthreads();
    }
#pragma unroll
    for (int k = 0; k < 4; k++) {
        int row = oty0 + k * 8;
        int gidx = b * HW + (ty0 + row) * Wn + (tx0 + otx);
        float mux = acc[0][k], muy = acc[1][k], mxx = acc[2][k], myy = acc[3][k], mxy = acc[4][k];
        float sx2 = fmaxf(mxx - mux * mux, 0.f);
        float sy2 = fmaxf(myy - muy * muy, 0.f);
        float sxy = mxy - mux * muy;
        float num = (2.f * mux * muy + C1C) * (2.f * sxy + C2C);
        float den = (mux * mux + muy * muy + C1C) * (sx2 + sy2 + C2C);
        float ss = num / (den + DEN_EPS);
        float tv = (ss + 1.f) * 0.5f;
        tv = fminf(fmaxf(tv, 0.f), 1.f);
        tau[gidx] = tv;
        varg[gidx] = sy2;   // raw max(var,0); +eps applied downstream
        if (WRITE_MUG) muG[gidx] = muy;
    }
}

// ---------------- K6: partial sums of 1/(chi_g+eps), 1/(nu+theta) ----------------
__global__ void k_nu(const float* __restrict__ v1, const float* __restrict__ vr,
                     const float* __restrict__ t1, const float* __restrict__ tr,
                     float* __restrict__ s1, float* __restrict__ s2) {
    __shared__ float a1[256], a2[256];
    int t = threadIdx.x;
    int base = blockIdx.x * 1024;
    float l1 = 0.f, l2 = 0.f;
#pragma unroll
    for (int k = 0; k < 4; k++) {
        int p = base + t + k * 256;
        float chig = sqrtf(v1[p] + EPSC) * sqrtf(vr[p] + EPSC);
        float nu = fmaxf(t1[p] * tr[p], 0.f);
        l1 += 1.f / (chig + EPSC);
        l2 += 1.f / (nu + THETAC);
    }
    a1[t] = l1; a2[t] = l2;
    __syncthreads();
    for (int s = 128; s > 0; s >>= 1) {
        if (t < s) { a1[t] += a1[t + s]; a2[t] += a2[t + s]; }
        __syncthreads();
    }
    if (t == 0) { s1[blockIdx.x] = a1[0]; s2[blockIdx.x] = a2[0]; }
}

__global__ void k_nured(const float* __restrict__ s1, const float* __restrict__ s2,
                        float* __restrict__ sc) {
    __shared__ float a1[256], a2[256];
    int t = threadIdx.x, b = blockIdx.x;
    a1[t] = s1[b * 256 + t];
    a2[t] = s2[b * 256 + t];
    __syncthreads();
    for (int s = 128; s > 0; s >>= 1) {
        if (t < s) { a1[t] += a1[t + s]; a2[t] += a2[t + s]; }
        __syncthreads();
    }
    if (t == 0) {
        sc[8 + b] = a1[0] / (float)HW;   // inv_mean_chi
        sc[12 + b] = a2[0] / (float)HW;  // inv_mean_nu
    }
}

// ---------------- K7: per-pixel P, D planes ----------------
__global__ void k_pd(const float* __restrict__ chi, const float* __restrict__ v1,
                     const float* __restrict__ vr, const float* __restrict__ t1,
                     const float* __restrict__ tr, const float* __restrict__ sc,
                     float* __restrict__ P, float* __restrict__ D) {
    int p = blockIdx.x * 256 + threadIdx.x;
    if (p >= NP) return;
    int b = p / HW;
    float mu = sc[b], eta = sc[4 + b], imc = sc[8 + b], imn = sc[12 + b];
    float gamma = 1.f / (1.f + expf(-eta * (chi[p] - mu)));
    float chig = sqrtf(v1[p] + EPSC) * sqrtf(vr[p] + EPSC);
    float GG = (chig + EPSC) * imc;
    float w_e = 1.0f / (GG + EPSC);                 // LAM = 1
    float nu = fmaxf(t1[p] * tr[p], 0.f);
    float GS = (nu + THETAC) * imn;
    float w_s = gamma / (GS + EPSC);
    P[p] = w_e * gamma + w_s * tr[p];
    D[p] = vr[p] + EPSC + w_e + w_s + EPSC;         // varG(+eps) + w_e + w_s + eps
}

// ---------------- K8: per-channel a,b via box5(X), box5(X*G) ----------------
template <int RAD>
__global__ void k_ab(const float* __restrict__ X, const float* __restrict__ G,
                     const float* __restrict__ muG, const float* __restrict__ P,
                     const float* __restrict__ D, float* __restrict__ A,
                     float* __restrict__ Bb) {
    constexpr int HALO = TS + 2 * RAD;
    constexpr int K = 2 * RAD + 1;
    __shared__ float sx[HALO * HALO], sg[HALO * HALO], hs[HALO * TS];
    int t = threadIdx.x;
    int pc = blockIdx.y;      // b*Cn + c
    int b = pc / Cn;
    constexpr int tiles_x = Wn / TS;
    int tx0 = (blockIdx.x % tiles_x) * TS;
    int ty0 = (blockIdx.x / tiles_x) * TS;
    const float* Xp = X + (size_t)pc * HW;
    const float* Gp = G + (size_t)b * HW;
    for (int i = t; i < HALO * HALO; i += 256) {
        int ly = i / HALO, lx = i % HALO;
        int gy = refl(ty0 - RAD + ly, Hn), gx = refl(tx0 - RAD + lx, Wn);
        sx[i] = Xp[gy * Wn + gx];
        sg[i] = Gp[gy * Wn + gx];
    }
    __syncthreads();
    int otx = t % TS, oty0 = t / TS;
    float mx[4], mxg[4];
    const float inv_area = 1.f / (float)(K * K);
#pragma unroll
    for (int p = 0; p < 2; p++) {
        for (int i = t; i < HALO * TS; i += 256) {
            int y = i / TS, ox = i % TS;
            float s = 0.f;
#pragma unroll
            for (int dx = 0; dx < K; dx++) {
                int idx = y * HALO + ox + dx;
                s += p ? sx[idx] * sg[idx] : sx[idx];
            }
            hs[i] = s;
        }
        __syncthreads();
#pragma unroll
        for (int k = 0; k < 4; k++) {
            int row = oty0 + k * 8;
            float s = 0.f;
#pragma unroll
            for (int dy = 0; dy < K; dy++) s += hs[(row + dy) * TS + otx];
            if (p) mxg[k] = s * inv_area; else mx[k] = s * inv_area;
        }
        __syncthreads();
    }
#pragma unroll
    for (int k = 0; k < 4; k++) {
        int row = oty0 + k * 8;
        int poff = (ty0 + row) * Wn + tx0 + otx;
        int gp = b * HW + poff;
        float mg = muG[gp], Pv = P[gp], Dv = D[gp];
        float a = (mxg[k] - mg * mx[k] + Pv) / Dv;
        A[pc * HW + poff] = a;
        Bb[pc * HW + poff] = mx[k] - a * mg;
    }
}

// ---------------- K9: out = box5(a)*G + box5(b) ----------------
template <int RAD>
__global__ void k_out(const float* __restrict__ A, const float* __restrict__ Bb,
                      const float* __restrict__ G, float* __restrict__ out) {
    constexpr int HALO = TS + 2 * RAD;
    constexpr int K = 2 * RAD + 1;
    __shared__ float sa[HALO * HALO], sb[HALO * HALO], hs[HALO * TS];
    int t = threadIdx.x;
    int pc = blockIdx.y;
    int b = pc / Cn;
    constexpr int tiles_x = Wn / TS;
    int tx0 = (blockIdx.x % tiles_x) * TS;
    int ty0 = (blockIdx.x / tiles_x) * TS;
    const float* Ap = A + (size_t)pc * HW;
    const float* Bp = Bb + (size_t)pc * HW;
    for (int i = t; i < HALO * HALO; i += 256) {
        int ly = i / HALO, lx = i % HALO;
        int gy = refl(ty0 - RAD + ly, Hn), gx = refl(tx0 - RAD + lx, Wn);
        sa[i] = Ap[gy * Wn + gx];
        sb[i] = Bp[gy * Wn + gx];
    }
    __syncthreads();
    int otx = t % TS, oty0 = t / TS;
    float ma[4], mb[4];
    const float inv_area = 1.f / (float)(K * K);
#pragma unroll
    for (int p = 0; p < 2; p++) {
        for (int i = t; i < HALO * TS; i += 256) {
            int y = i / TS, ox = i % TS;
            const float* src = p ? sb : sa;
            float s = 0.f;
#pragma unroll
            for (int dx = 0; dx < K; dx++) s += src[y * HALO + ox + dx];
            hs[i] = s;
        }
        __syncthreads();
#pragma unroll
        for (int k = 0; k < 4; k++) {
            int row = oty0 + k * 8;
            float s = 0.f;
#pragma unroll
            for (int dy = 0; dy < K; dy++) s += hs[(row + dy) * TS + otx];
            if (p) mb[k] = s * inv_area; else ma[k] = s * inv_area;
        }
        __syncthreads();
    }
    const float* Gp = G + (size_t)b * HW;
#pragma unroll
    for (int k = 0; k < 4; k++) {
        int row = oty0 + k * 8;
        int poff = (ty0 + row) * Wn + tx0 + otx;
        out[pc * HW + poff] = ma[k] * Gp[poff] + mb[k];
    }
}

extern "C" void kernel_launch(void* const* d_in, const int* in_sizes, int n_in,
                              void* d_out, int out_size, void* d_ws, size_t ws_size,
                              hipStream_t stream) {
    const float* X = (const float*)d_in[0];
    const float* G = (const float*)d_in[1];
    float* out = (float*)d_out;
    float* ws = (float*)d_ws;

    float* Xs   = ws + 0 * (size_t)NP;
    float* chi  = ws + 1 * (size_t)NP;
    float* taur = ws + 2 * (size_t)NP;
    float* tau1 = ws + 3 * (size_t)NP;
    float* v1   = ws + 4 * (size_t)NP;
    float* vr   = ws + 5 * (size_t)NP;
    float* muG  = ws + 6 * (size_t)NP;
    float* Pp   = ws + 7 * (size_t)NP;
    float* Dd   = ws + 8 * (size_t)NP;
    float* A    = ws + 9 * (size_t)NP;
    float* Bb   = A + (size_t)NX;
    float* psum = Bb + (size_t)NX;
    float* pmin = psum + 1024;
    float* s1   = pmin + 1024;
    float* s2   = s1 + 1024;
    float* sc   = s2 + 1024;   // 16 scalars: mu_chi[4], eta[4], inv_mean_chi[4], inv_mean_nu[4]

    dim3 blk(256);
    k_xs<<<NP / 256, blk, 0, stream>>>(X, Xs);
    k_chi<<<NP / 1024, blk, 0, stream>>>(G, chi, psum, pmin);
    k_chired<<<4, blk, 0, stream>>>(psum, pmin, sc);

    dim3 gplane((Wn / TS) * (Hn / TS), Bn);
    k_ssim<5, true><<<gplane, blk, 0, stream>>>(Xs, G, taur, vr, muG);
    k_ssim<1, false><<<gplane, blk, 0, stream>>>(Xs, G, tau1, v1, muG);

    k_nu<<<NP / 1024, blk, 0, stream>>>(v1, vr, tau1, taur, s1, s2);
    k_nured<<<4, blk, 0, stream>>>(s1, s2, sc);
    k_pd<<<NP / 256, blk, 0, stream>>>(chi, v1, vr, tau1, taur, sc, Pp, Dd);

    dim3 gchan((Wn / TS) * (Hn / TS), Bn * Cn);
    k_ab<5><<<gchan, blk, 0, stream>>>(X, G, muG, Pp, Dd, A, Bb);
    k_out<5><<<gchan, blk, 0, stream>>>(A, Bb, G, out);
}

// Round 2
// 156.856 us; speedup vs baseline: 1.4213x; 1.4213x over previous
//
#include <hip/hip_runtime.h>
#include <math.h>

#define EPSC 1e-6f
#define THETAC 1e-3f
#define C1C 1e-4f
#define C2C 9e-4f
#define DEN_EPS 1e-12f

constexpr int Bn = 4, Cn = 16, Hn = 512, Wn = 512;
constexpr int HW = Hn * Wn;          // 262144 = 2^18
constexpr int NP = Bn * HW;          // 1048576
constexpr int NX = Bn * Cn * HW;     // 16777216
constexpr int TS = 32, RAD = 5, K = 11;
constexpr int HALO = TS + 2 * RAD;   // 42
constexpr int PITCH = 43;            // padded LDS pitch for halo arrays
constexpr int HP = 33;               // padded pitch for horizontal-sum buffer
constexpr int ASZ = HALO * PITCH;    // 1806
constexpr int HSZ = HALO * HP;       // 1386
constexpr int tiles_x = Wn / TS;     // 16
constexpr int NT = (Wn / TS) * (Hn / TS); // 256 tiles per plane

__device__ __forceinline__ int refl(int i, int n) {
    if (i < 0) i = -i;
    if (i >= n) i = 2 * n - 2 - i;
    return i;
}

// XCD-aware tile swizzle: 256 tiles -> each of 8 XCDs gets 32 contiguous tiles
__device__ __forceinline__ int swz_tile(int x) { return (x & 7) * (NT / 8) + (x >> 3); }

// horizontal box-11 running sums for npl planes at sp[pl*ASZ] -> hs[pl*HSZ]
// thread layout: t < 84*npl : pl = t/84, y = (t%84)>>1, xhalf = (t&1)*16
__device__ __forceinline__ void hbox(const float* sp, float* hs, int t, int npl) {
    if (t < 84 * npl) {
        int pl = t / 84, rem = t - pl * 84;
        int y = rem >> 1, xh = (rem & 1) << 4;
        const float* src = sp + pl * ASZ + y * PITCH + xh;
        float* hd = hs + pl * HSZ + y * HP + xh;
        float s = 0.f;
#pragma unroll
        for (int dx = 0; dx < K; ++dx) s += src[dx];
        hd[0] = s;
#pragma unroll
        for (int j = 1; j < 16; ++j) { s += src[j + K - 1] - src[j - 1]; hd[j] = s; }
    }
}

// vertical box-11 running sums: thread owns column x, rows r0..r0+3 -> means m[4]
__device__ __forceinline__ void vbox(const float* hs, int x, int r0, float m[4]) {
    const float inv_area = 1.f / (float)(K * K);
    int base = r0 * HP + x;
    float s = 0.f;
#pragma unroll
    for (int dy = 0; dy < K; ++dy) s += hs[base + dy * HP];
    m[0] = s * inv_area;
#pragma unroll
    for (int j = 1; j < 4; ++j) {
        s += hs[base + (j + K - 1) * HP] - hs[base + (j - 1) * HP];
        m[j] = s * inv_area;
    }
}

// ---------------- K1: Xs = mean over channels (float4) ----------------
__global__ void __launch_bounds__(256) k_xs(const float* __restrict__ X, float* __restrict__ Xs) {
    constexpr int NP4 = NP / 4, HW4 = HW / 4;
    int i = blockIdx.x * 256 + threadIdx.x;
    if (i >= NP4) return;
    int b = i / HW4, off = i - b * HW4;
    const float4* xp = (const float4*)(X + (size_t)b * Cn * HW) + off;
    float4 s = make_float4(0.f, 0.f, 0.f, 0.f);
#pragma unroll
    for (int c = 0; c < Cn; ++c) {
        float4 v = xp[(size_t)c * HW4];
        s.x += v.x; s.y += v.y; s.z += v.z; s.w += v.w;
    }
    const float sc = 1.0f / Cn;
    s.x *= sc; s.y *= sc; s.z *= sc; s.w *= sc;
    ((float4*)Xs)[i] = s;
}

// ---------------- K2: chi + per-block {sum,min} ----------------
__global__ void __launch_bounds__(256) k_chi(const float* __restrict__ G, float* __restrict__ chi,
                      float* __restrict__ psum, float* __restrict__ pmin) {
    __shared__ float ssum[256], smin[256];
    int t = threadIdx.x;
    int base = blockIdx.x * 1024;
    float ls = 0.f, lm = 1e30f;
#pragma unroll
    for (int k = 0; k < 4; ++k) {
        int p = base + t + k * 256;
        int off = p & (HW - 1);
        int y = off / Wn, x = off & (Wn - 1);
        float g = G[p];
        float gx = (x < Wn - 1) ? G[p + 1] - g : 0.f;
        float gy = (y < Hn - 1) ? G[p + Wn] - g : 0.f;
        float c = sqrtf(gx * gx + gy * gy + EPSC);
        chi[p] = c;
        ls += c;
        lm = fminf(lm, c);
    }
    ssum[t] = ls; smin[t] = lm;
    __syncthreads();
    for (int s = 128; s > 0; s >>= 1) {
        if (t < s) { ssum[t] += ssum[t + s]; smin[t] = fminf(smin[t], smin[t + s]); }
        __syncthreads();
    }
    if (t == 0) { psum[blockIdx.x] = ssum[0]; pmin[blockIdx.x] = smin[0]; }
}

__global__ void __launch_bounds__(256) k_chired(const float* __restrict__ psum, const float* __restrict__ pmin,
                         float* __restrict__ sc) {
    __shared__ float ssum[256], smin[256];
    int t = threadIdx.x, b = blockIdx.x;
    ssum[t] = psum[b * 256 + t];
    smin[t] = pmin[b * 256 + t];
    __syncthreads();
    for (int s = 128; s > 0; s >>= 1) {
        if (t < s) { ssum[t] += ssum[t + s]; smin[t] = fminf(smin[t], smin[t + s]); }
        __syncthreads();
    }
    if (t == 0) {
        float mu = ssum[0] / (float)HW;
        sc[b] = mu;
        sc[4 + b] = fmaxf(mu - smin[0], EPSC);
    }
}

// ---------------- K3: merged ssim r=5 & r=1 + plane outputs + reductions ----------------
__global__ void __launch_bounds__(256) k_ssim(
        const float* __restrict__ Xs, const float* __restrict__ G,
        float* __restrict__ muG, float* __restrict__ varGr, float* __restrict__ taur,
        float* __restrict__ chig, float* __restrict__ nu,
        float* __restrict__ ps1, float* __restrict__ ps2) {
    __shared__ float arrs[5 * ASZ];   // x, g, xx, gg, xg halos (padded pitch 43)
    __shared__ float hs[2 * HSZ];
    __shared__ float red1[256], red2[256];
    int t = threadIdx.x;
    int b = blockIdx.y;
    int tile = swz_tile(blockIdx.x);
    int tx0 = (tile % tiles_x) * TS, ty0 = (tile / tiles_x) * TS;
    const float* Xp = Xs + (size_t)b * HW;
    const float* Gp = G + (size_t)b * HW;
    for (int i = t; i < HALO * HALO; i += 256) {
        int ly = i / HALO, lx = i - ly * HALO;
        int gy = refl(ty0 - RAD + ly, Hn), gx = refl(tx0 - RAD + lx, Wn);
        float vx = Xp[gy * Wn + gx], vg = Gp[gy * Wn + gx];
        int o = ly * PITCH + lx;
        arrs[o] = vx;
        arrs[ASZ + o] = vg;
        arrs[2 * ASZ + o] = vx * vx;
        arrs[3 * ASZ + o] = vg * vg;
        arrs[4 * ASZ + o] = vx * vg;
    }
    __syncthreads();

    int x = t & 31, g = t >> 5, r0 = g * 4;
    float acc[5][4];
#pragma unroll
    for (int round = 0; round < 3; ++round) {
        const int npl = (round < 2) ? 2 : 1;
        hbox(arrs + 2 * round * ASZ, hs, t, npl);
        __syncthreads();
#pragma unroll
        for (int pl = 0; pl < npl; ++pl) vbox(hs + pl * HSZ, x, r0, acc[2 * round + pl]);
        __syncthreads();
    }

    // r=1 box means for all 5 planes (separable 3-tap, 6 hrows per thread-column)
    float m1[5][4];
#pragma unroll
    for (int p = 0; p < 5; ++p) {
        float h3[6];
#pragma unroll
        for (int j = 0; j < 6; ++j) {
            int bb = p * ASZ + (r0 + 4 + j) * PITCH + (x + 4);
            h3[j] = arrs[bb] + arrs[bb + 1] + arrs[bb + 2];
        }
#pragma unroll
        for (int j = 0; j < 4; ++j)
            m1[p][j] = (h3[j] + h3[j + 1] + h3[j + 2]) * (1.f / 9.f);
    }

    float l1 = 0.f, l2 = 0.f;
#pragma unroll
    for (int j = 0; j < 4; ++j) {
        float mux = acc[0][j], mug = acc[1][j], mxx = acc[2][j], mgg = acc[3][j], mxy = acc[4][j];
        float sx2 = fmaxf(mxx - mux * mux, 0.f);
        float sg2 = fmaxf(mgg - mug * mug, 0.f);
        float sxy = mxy - mux * mug;
        float num = (2.f * mux * mug + C1C) * (2.f * sxy + C2C);
        float den = (mux * mux + mug * mug + C1C) * (sx2 + sg2 + C2C);
        float tr_ = fminf(fmaxf((num / (den + DEN_EPS) + 1.f) * 0.5f, 0.f), 1.f);

        float n0 = m1[0][j], n1 = m1[1][j], n2 = m1[2][j], n3 = m1[3][j], n4 = m1[4][j];
        float sx21 = fmaxf(n2 - n0 * n0, 0.f);
        float sg21 = fmaxf(n3 - n1 * n1, 0.f);
        float sxy1 = n4 - n0 * n1;
        float num1 = (2.f * n0 * n1 + C1C) * (2.f * sxy1 + C2C);
        float den1 = (n0 * n0 + n1 * n1 + C1C) * (sx21 + sg21 + C2C);
        float t1_ = fminf(fmaxf((num1 / (den1 + DEN_EPS) + 1.f) * 0.5f, 0.f), 1.f);

        float chig_ = sqrtf(sg21 + EPSC) * sqrtf(sg2 + EPSC);
        float nu_ = fmaxf(t1_ * tr_, 0.f);
        int gp = b * HW + (ty0 + r0 + j) * Wn + (tx0 + x);
        muG[gp] = mug;
        varGr[gp] = sg2;
        taur[gp] = tr_;
        chig[gp] = chig_;
        nu[gp] = nu_;
        l1 += 1.f / (chig_ + EPSC);
        l2 += 1.f / (nu_ + THETAC);
    }
    red1[t] = l1; red2[t] = l2;
    __syncthreads();
    for (int s = 128; s > 0; s >>= 1) {
        if (t < s) { red1[t] += red1[t + s]; red2[t] += red2[t + s]; }
        __syncthreads();
    }
    if (t == 0) {
        ps1[b * NT + blockIdx.x] = red1[0];
        ps2[b * NT + blockIdx.x] = red2[0];
    }
}

__global__ void __launch_bounds__(256) k_nured(const float* __restrict__ s1, const float* __restrict__ s2,
                        float* __restrict__ sc) {
    __shared__ float a1[256], a2[256];
    int t = threadIdx.x, b = blockIdx.x;
    a1[t] = s1[b * 256 + t];
    a2[t] = s2[b * 256 + t];
    __syncthreads();
    for (int s = 128; s > 0; s >>= 1) {
        if (t < s) { a1[t] += a1[t + s]; a2[t] += a2[t + s]; }
        __syncthreads();
    }
    if (t == 0) {
        sc[8 + b] = a1[0] / (float)HW;
        sc[12 + b] = a2[0] / (float)HW;
    }
}

// ---------------- K4: per-pixel P, D planes ----------------
__global__ void __launch_bounds__(256) k_pd(
        const float* __restrict__ chi, const float* __restrict__ chig,
        const float* __restrict__ nu, const float* __restrict__ taur,
        const float* __restrict__ vr, const float* __restrict__ sc,
        float* __restrict__ P, float* __restrict__ D) {
    int p = blockIdx.x * 256 + threadIdx.x;
    if (p >= NP) return;
    int b = p >> 18;
    float mu = sc[b], eta = sc[4 + b], imc = sc[8 + b], imn = sc[12 + b];
    float gamma = 1.f / (1.f + expf(-eta * (chi[p] - mu)));
    float GG = (chig[p] + EPSC) * imc;
    float w_e = 1.0f / (GG + EPSC);                 // LAM = 1
    float GS = (nu[p] + THETAC) * imn;
    float w_s = gamma / (GS + EPSC);
    P[p] = w_e * gamma + w_s * taur[p];
    D[p] = vr[p] + EPSC + w_e + w_s + EPSC;
}

// ---------------- K5: per-channel a,b via sliding box5(X), box5(X*G) ----------------
__global__ void __launch_bounds__(256) k_ab(
        const float* __restrict__ X, const float* __restrict__ G,
        const float* __restrict__ muG, const float* __restrict__ P,
        const float* __restrict__ D, float* __restrict__ A, float* __restrict__ Bb) {
    __shared__ float sp[2 * ASZ];    // plane0 = X, plane1 = X*G
    __shared__ float hs[2 * HSZ];
    int t = threadIdx.x;
    int pc = blockIdx.y, b = pc >> 4;
    int tile = swz_tile(blockIdx.x);
    int tx0 = (tile % tiles_x) * TS, ty0 = (tile / tiles_x) * TS;
    const float* Xp = X + (size_t)pc * HW;
    const float* Gp = G + (size_t)b * HW;
    for (int i = t; i < HALO * HALO; i += 256) {
        int ly = i / HALO, lx = i - ly * HALO;
        int gy = refl(ty0 - RAD + ly, Hn), gx = refl(tx0 - RAD + lx, Wn);
        float vx = Xp[gy * Wn + gx], vg = Gp[gy * Wn + gx];
        int o = ly * PITCH + lx;
        sp[o] = vx;
        sp[ASZ + o] = vx * vg;
    }
    __syncthreads();
    hbox(sp, hs, t, 2);
    __syncthreads();
    int x = t & 31, g = t >> 5, r0 = g * 4;
    float mx[4], mxg[4];
    vbox(hs, x, r0, mx);
    vbox(hs + HSZ, x, r0, mxg);
#pragma unroll
    for (int j = 0; j < 4; ++j) {
        int py = ty0 + r0 + j, px = tx0 + x;
        int gp = b * HW + py * Wn + px;
        float mg = muG[gp], Pv = P[gp], Dv = D[gp];
        float a = (mxg[j] - mg * mx[j] + Pv) / Dv;
        size_t o = (size_t)pc * HW + py * Wn + px;
        A[o] = a;
        Bb[o] = mx[j] - a * mg;
    }
}

// ---------------- K6: out = box5(a)*G + box5(b) ----------------
__global__ void __launch_bounds__(256) k_out(
        const float* __restrict__ A, const float* __restrict__ Bb,
        const float* __restrict__ G, float* __restrict__ out) {
    __shared__ float sp[2 * ASZ];
    __shared__ float hs[2 * HSZ];
    int t = threadIdx.x;
    int pc = blockIdx.y, b = pc >> 4;
    int tile = swz_tile(blockIdx.x);
    int tx0 = (tile % tiles_x) * TS, ty0 = (tile / tiles_x) * TS;
    const float* Ap = A + (size_t)pc * HW;
    const float* Bp = Bb + (size_t)pc * HW;
    for (int i = t; i < HALO * HALO; i += 256) {
        int ly = i / HALO, lx = i - ly * HALO;
        int gy = refl(ty0 - RAD + ly, Hn), gx = refl(tx0 - RAD + lx, Wn);
        int src = gy * Wn + gx, o = ly * PITCH + lx;
        sp[o] = Ap[src];
        sp[ASZ + o] = Bp[src];
    }
    __syncthreads();
    hbox(sp, hs, t, 2);
    __syncthreads();
    int x = t & 31, g = t >> 5, r0 = g * 4;
    float ma[4], mb[4];
    vbox(hs, x, r0, ma);
    vbox(hs + HSZ, x, r0, mb);
    const float* Gp = G + (size_t)b * HW;
#pragma unroll
    for (int j = 0; j < 4; ++j) {
        int py = ty0 + r0 + j, px = tx0 + x;
        int poff = py * Wn + px;
        out[(size_t)pc * HW + poff] = ma[j] * Gp[poff] + mb[j];
    }
}

extern "C" void kernel_launch(void* const* d_in, const int* in_sizes, int n_in,
                              void* d_out, int out_size, void* d_ws, size_t ws_size,
                              hipStream_t stream) {
    const float* X = (const float*)d_in[0];
    const float* G = (const float*)d_in[1];
    float* out = (float*)d_out;
    float* ws = (float*)d_ws;

    float* Xs   = ws + 0 * (size_t)NP;
    float* chi  = ws + 1 * (size_t)NP;
    float* taur = ws + 2 * (size_t)NP;
    float* vr   = ws + 3 * (size_t)NP;
    float* muG  = ws + 4 * (size_t)NP;
    float* chig = ws + 5 * (size_t)NP;
    float* nu   = ws + 6 * (size_t)NP;
    float* Pp   = ws + 7 * (size_t)NP;
    float* Dd   = ws + 8 * (size_t)NP;
    float* A    = ws + 9 * (size_t)NP;
    float* Bb   = A + (size_t)NX;
    float* psum = Bb + (size_t)NX;
    float* pmin = psum + 1024;
    float* ps1  = pmin + 1024;
    float* ps2  = ps1 + 1024;
    float* sc   = ps2 + 1024;   // 16 scalars

    dim3 blk(256);
    k_xs<<<(NP / 4) / 256, blk, 0, stream>>>(X, Xs);
    k_chi<<<NP / 1024, blk, 0, stream>>>(G, chi, psum, pmin);
    k_chired<<<4, blk, 0, stream>>>(psum, pmin, sc);

    dim3 gplane(NT, Bn);
    k_ssim<<<gplane, blk, 0, stream>>>(Xs, G, muG, vr, taur, chig, nu, ps1, ps2);
    k_nured<<<4, blk, 0, stream>>>(ps1, ps2, sc);
    k_pd<<<NP / 256, blk, 0, stream>>>(chi, chig, nu, taur, vr, sc, Pp, Dd);

    dim3 gchan(NT, Bn * Cn);
    k_ab<<<gchan, blk, 0, stream>>>(X, G, muG, Pp, Dd, A, Bb);
    k_out<<<gchan, blk, 0, stream>>>(A, Bb, G, out);
}